// Round 5
// baseline (1919.970 us; speedup 1.0000x reference)
//
#include <hip/hip_runtime.h>
#include <hip/hip_fp16.h>
#include <cstdio>

// EmbeddingCellLSTM: B=32, S=2048, IN=64, EMB=32, H=256, 4H=1024
//  k1 pack_kernel : W_hh fp32 -> i8 (scale 2032) 16B K-fragments (lane&15 -> row, lane>>4 -> K-chunk).
//                   Used as MFMA *B* operand now; packing identical to the verified A-frag layout.
//  k2 zx_kernel   : zx = (concat(x,emb) @ W_ih^T + b) fp16; block = 64-row stripe, stages x once.
//  k3 lstm_kernel : TRANSPOSED MFMA: acc[g] = mfma(A=h_broadcast, B=W_frag, C=zero).
//                   D col = lane&15 = weight row -> lane n holds z[g][w*16+n] in reg0 for all 4
//                   gates. Kills the cndmask select tree, 12 of 16 accvgpr_reads, all 4 gate
//                   bpermutes, and the per-step acc zero-init (persistent zero C). Each lane does
//                   the full i,f,g,o activation + c/h update for its unit (x4 replicas across q);
//                   q==0 lanes write i8 h feedback + fp32 out. Wave-priority stagger kept.
//  Measured r4: step=1842cyc, matrix busy 1024 (16cyc/MFMA -> floor 874us), VALU busy ~1000.
//  This round targets the VALU side: ~-45 insts/wave/step -> step ~1250-1450 cyc.

#define WPK_OFF (134217728u)   // zx = 32*2048*1024*2 bytes, then wpk 256 KB

typedef int v4i __attribute__((ext_vector_type(4)));

static __device__ __forceinline__ unsigned short f16bits(float v) {
  _Float16 h = (_Float16)v;
  return __builtin_bit_cast(unsigned short, h);
}

static __device__ __forceinline__ float h2f(unsigned short b) {
  return (float)__builtin_bit_cast(_Float16, b);
}

// ---------------- k1: pack W_hh -> i8 MFMA K-fragments ----------------
// tile = g*4+c ; thread t -> w=t>>6, lane: m=lane&15 (row), q=lane>>4
// frag byte j = W[g*256 + 16w + m][c*64 + q*16 + j] ; wq = rint(w*2032), |w|<1/16 -> |wq|<=127
__global__ __launch_bounds__(1024) void pack_kernel(const float* __restrict__ Whh,
                                                    uint4* __restrict__ wpk) {
  int tile = blockIdx.x;            // 0..15
  int g = tile >> 2, c = tile & 3;
  int t = threadIdx.x;
  int w = t >> 6, lane = t & 63, m = lane & 15, q = lane >> 4;
  int row = g * 256 + w * 16 + m;
  const float* src = Whh + row * 256 + c * 64 + q * 16;
  unsigned int pk[4];
#pragma unroll
  for (int d = 0; d < 4; d++) {
    unsigned int v = 0;
#pragma unroll
    for (int e = 0; e < 4; e++) {
      int qv = (int)rintf(src[d * 4 + e] * 2032.0f);
      v |= ((unsigned int)(qv & 255)) << (8 * e);
    }
    pk[d] = v;
  }
  uint4 o; o.x = pk[0]; o.y = pk[1]; o.z = pk[2]; o.w = pk[3];
  wpk[tile * 1024 + t] = o;
}

// ---------------- k2: zx = concat(x,emb) @ W_ih^T + b (fp16, natural row order) ----------------
// One block per 64-row stripe; x/emb staged once, 16 column tiles looped in-block.
__global__ __launch_bounds__(256) void zx_kernel(const float* __restrict__ x,
                                                 const float* __restrict__ emb,
                                                 const float* __restrict__ Wih,
                                                 const float* __restrict__ bias,
                                                 unsigned short* __restrict__ zx) {
  __shared__ __align__(16) float XeT[96][68];
  __shared__ __align__(16) float WT[96][68];
  int mt = blockIdx.x;              // 0..1023
  int m0 = mt * 64;
  int tid = threadIdx.x;
  for (int idx = tid; idx < 6144; idx += 256) {
    int r = idx / 96, k = idx - r * 96;
    size_t m = (size_t)(m0 + r);
    float v = (k < 64) ? x[m * 64 + k] : emb[m * 32 + (k - 64)];
    XeT[k][r] = v;
  }
  int ty = tid >> 4, tx = tid & 15;
  int r0 = ty * 4, c0 = tx * 4;
  for (int nt = 0; nt < 16; nt++) {
    int n0 = nt * 64;
    __syncthreads();                // protect WT vs previous iter's readers (covers XeT stage on iter 0)
    for (int idx = tid; idx < 6144; idx += 256) {
      int c = idx / 96, k = idx - c * 96;
      WT[k][c] = Wih[(size_t)(n0 + c) * 96 + k];
    }
    __syncthreads();
    float acc[4][4] = {};
    for (int k = 0; k < 96; k++) {
      float4 a = *(const float4*)&XeT[k][r0];
      float4 wv4 = *(const float4*)&WT[k][c0];
      float av[4] = {a.x, a.y, a.z, a.w};
      float wv[4] = {wv4.x, wv4.y, wv4.z, wv4.w};
#pragma unroll
      for (int i = 0; i < 4; i++)
#pragma unroll
        for (int jj = 0; jj < 4; jj++) acc[i][jj] += av[i] * wv[jj];
    }
#pragma unroll
    for (int i = 0; i < 4; i++) {
      size_t m = (size_t)(m0 + r0 + i);
#pragma unroll
      for (int jj = 0; jj < 4; jj++) {
        int col = n0 + c0 + jj;
        zx[m * 1024 + (size_t)col] = f16bits(acc[i][jj] + bias[col]);
      }
    }
  }
}

// ---------------- k3: persistent per-batch LSTM (transposed i8 MFMA) ----------------
__global__ __launch_bounds__(1024, 4) void lstm_kernel(const unsigned short* __restrict__ zx,
                                                       const v4i* __restrict__ wpk,
                                                       float* __restrict__ out) {
  __shared__ __align__(16) char hq[2][256];
  const int t = threadIdx.x, b = blockIdx.x;
  const int w = t >> 6, lane = t & 63, q = lane >> 4, n = lane & 15;

  // full W_hh residency: 16 frags x 16B i8 = 64 regs (B-operand; AGPR-friendly)
  v4i wf[16];
#pragma unroll
  for (int i = 0; i < 16; i++) wf[i] = wpk[i * 1024 + t];

  if (t < 128) ((unsigned int*)hq)[t] = 0;   // zero both h buffers (2x256 i8)
  __syncthreads();

  // wave-priority stagger: same-SIMD waves at prio 3,2,1,0 (robust to either wave->SIMD map)
  {
    int pr = 3 - (((w >> 2) ^ w) & 3);
    if (pr == 3) __builtin_amdgcn_s_setprio(3);
    else if (pr == 2) __builtin_amdgcn_s_setprio(2);
    else if (pr == 1) __builtin_amdgcn_s_setprio(1);
  }

  const float dq = 1.0f / (2032.0f * 127.0f);
  const int u = w * 16 + n;                       // this lane's unit (replicated across q)
  const unsigned short* zpu = zx + (size_t)b * (2048u * 1024u) + u;
  const bool wr = (q == 0);
  float* op = out + (size_t)b * (2048u * 256u) + u;
  char* hn0 = &hq[0][u];
  const v4i zerov = {0, 0, 0, 0};                 // persistent MFMA C operand (D != C)

  float cst = 0.f, hlast = 0.f;
  unsigned short za0 = zpu[0], za1 = zpu[256], za2 = zpu[512], za3 = zpu[768];
  unsigned short zb0 = zpu[1024], zb1 = zpu[1280], zb2 = zpu[1536], zb3 = zpu[1792];

  for (int s = 0; s < 2048; s++) {
    const char* hc = hq[s & 1];
    int sp = s + 2; if (sp > 2047) sp = 2047;
    const unsigned short* zn = zpu + ((size_t)sp << 10);
    unsigned short zc0 = zn[0], zc1 = zn[256], zc2 = zn[512], zc3 = zn[768];

    // A-frags: broadcast h chunk (16B per 16-lane group -> all M rows = h)
    v4i bq[4];
#pragma unroll
    for (int c = 0; c < 4; c++) bq[c] = *(const v4i*)(hc + c * 64 + q * 16);

    // acc[g] col n = z[g][w*16+n]; rows are h-replicas -> reg 0 suffices
    v4i acc[4];
#pragma unroll
    for (int gg = 0; gg < 4; gg++)
      acc[gg] = __builtin_amdgcn_mfma_i32_16x16x64_i8(bq[0], wf[gg * 4 + 0], zerov, 0, 0, 0);
#pragma unroll
    for (int c = 1; c < 4; c++)
#pragma unroll
      for (int gg = 0; gg < 4; gg++)
        acc[gg] = __builtin_amdgcn_mfma_i32_16x16x64_i8(bq[c], wf[gg * 4 + c], acc[gg], 0, 0, 0);

    float z0 = (float)acc[0][0] * dq + h2f(za0);   // i
    float z1 = (float)acc[1][0] * dq + h2f(za1);   // f
    float z2 = (float)acc[2][0] * dq + h2f(za2);   // g
    float z3 = (float)acc[3][0] * dq + h2f(za3);   // o
    float si = __builtin_amdgcn_rcpf(1.f + __builtin_amdgcn_exp2f(-1.44269504f * z0));
    float sf = __builtin_amdgcn_rcpf(1.f + __builtin_amdgcn_exp2f(-1.44269504f * z1));
    float tg = 2.f * __builtin_amdgcn_rcpf(1.f + __builtin_amdgcn_exp2f(-2.88539008f * z2)) - 1.f;
    float so = __builtin_amdgcn_rcpf(1.f + __builtin_amdgcn_exp2f(-1.44269504f * z3));
    float cn = sf * cst + si * tg;
    float e2 = __builtin_amdgcn_exp2f(-2.88539008f * cn);
    float th = 2.f * __builtin_amdgcn_rcpf(1.f + e2) - 1.f;
    float h = so * th;
    cst = cn;
    hlast = h;
    if (wr) {
      hn0[((s & 1) ^ 1) * 256] = (char)(int)rintf(h * 127.0f);   // i8 h feedback
      op[(size_t)s * 256] = h;                                    // fp32 output
    }
    za0 = zb0; za1 = zb1; za2 = zb2; za3 = zb3;
    zb0 = zc0; zb1 = zc1; zb2 = zc2; zb3 = zc3;
    __syncthreads();
  }
  if (wr) {
    out[16777216u + (size_t)b * 256 + u] = hlast;          // final h
    out[16777216u + 8192u + (size_t)b * 256 + u] = cst;    // final c
  }
}

extern "C" void kernel_launch(void* const* d_in, const int* in_sizes, int n_in,
                              void* d_out, int out_size, void* d_ws, size_t ws_size,
                              hipStream_t stream) {
  const float* x = (const float*)d_in[0];
  const float* emb = (const float*)d_in[1];
  const float* W_ih = (const float*)d_in[2];
  const float* W_hh = (const float*)d_in[3];
  const float* bias = (const float*)d_in[4];
  float* out = (float*)d_out;
  char* ws = (char*)d_ws;

  unsigned short* zx = (unsigned short*)ws;
  uint4* wpk = (uint4*)(ws + WPK_OFF);

  size_t need = (size_t)WPK_OFF + 262144u;
  if (ws_size < need) {
    fprintf(stderr, "kernel_launch: ws too small: %zu < %zu\n", ws_size, need);
  }

  pack_kernel<<<dim3(16), dim3(1024), 0, stream>>>(W_hh, wpk);
  zx_kernel<<<dim3(1024), dim3(256), 0, stream>>>(x, emb, W_ih, bias, zx);
  lstm_kernel<<<dim3(32), dim3(1024), 0, stream>>>(zx, (const v4i*)wpk, out);
}

// Round 6
// 1715.997 us; speedup vs baseline: 1.1189x; 1.1189x over previous
//
#include <hip/hip_runtime.h>
#include <hip/hip_fp16.h>
#include <cstdio>

// EmbeddingCellLSTM: B=32, S=2048, IN=64, EMB=32, H=256, 4H=1024
//  k1 pack_kernel : W_hh fp32 -> i8 (scale 2032) 16B K-fragments (lane&15 -> W row, lane>>4 -> K-chunk).
//  k2 zx_kernel   : zx = (concat(x,emb) @ W_ih^T + b) fp16; block = 64-row stripe, stages x once.
//  k3 lstm_kernel : transposed MFMA (r5, verified): acc[g] = mfma(A=h_bcast, B=W_frag, C=0) ->
//                   lane (q,n) holds z[g][w*16+n] in acc[g][0] for ALL 4 gates, identical across
//                   q-groups. NEW (r6): activations DISTRIBUTED across q-replicas — lane (q,n)
//                   selects acc[q][0] (3 scalar cndmask), adds zx[gate q][u] (1 load/lane), does
//                   ONE sigmoid/tanh (4 trans/lane vs r5's 10 — r5 regression was +6 trans ≈
//                   +220 cyc/SIMD), then 4 wave-wide ds_bpermute gather i,f,g,o from lanes (g,n).
//                   c/h update replicated x4 across q; q==0 writes i8 h feedback + fp32 out.
//                   Wave-priority stagger kept (r4: ~+170 cyc/step).
//  Model: matrix floor 64 MFMA-inst/SIMD x 16 cyc = 1024 cyc/step (measured r4 & r5);
//  tail ~22 VALU + 4 trans + 4 bperm -> step ~1400-1500 cyc, k3 ~1200-1300 us.

#define WPK_OFF (134217728u)   // zx = 32*2048*1024*2 bytes, then wpk 256 KB

typedef int v4i __attribute__((ext_vector_type(4)));

static __device__ __forceinline__ unsigned short f16bits(float v) {
  _Float16 h = (_Float16)v;
  return __builtin_bit_cast(unsigned short, h);
}

static __device__ __forceinline__ float h2f(unsigned short b) {
  return (float)__builtin_bit_cast(_Float16, b);
}

// ---------------- k1: pack W_hh -> i8 MFMA K-fragments ----------------
// tile = g*4+c ; thread t -> w=t>>6, lane: m=lane&15 (row), q=lane>>4
// frag byte j = W[g*256 + 16w + m][c*64 + q*16 + j] ; wq = rint(w*2032), |w|<1/16 -> |wq|<=127
__global__ __launch_bounds__(1024) void pack_kernel(const float* __restrict__ Whh,
                                                    uint4* __restrict__ wpk) {
  int tile = blockIdx.x;            // 0..15
  int g = tile >> 2, c = tile & 3;
  int t = threadIdx.x;
  int w = t >> 6, lane = t & 63, m = lane & 15, q = lane >> 4;
  int row = g * 256 + w * 16 + m;
  const float* src = Whh + row * 256 + c * 64 + q * 16;
  unsigned int pk[4];
#pragma unroll
  for (int d = 0; d < 4; d++) {
    unsigned int v = 0;
#pragma unroll
    for (int e = 0; e < 4; e++) {
      int qv = (int)rintf(src[d * 4 + e] * 2032.0f);
      v |= ((unsigned int)(qv & 255)) << (8 * e);
    }
    pk[d] = v;
  }
  uint4 o; o.x = pk[0]; o.y = pk[1]; o.z = pk[2]; o.w = pk[3];
  wpk[tile * 1024 + t] = o;
}

// ---------------- k2: zx = concat(x,emb) @ W_ih^T + b (fp16, natural row order) ----------------
// One block per 64-row stripe; x/emb staged once, 16 column tiles looped in-block.
__global__ __launch_bounds__(256) void zx_kernel(const float* __restrict__ x,
                                                 const float* __restrict__ emb,
                                                 const float* __restrict__ Wih,
                                                 const float* __restrict__ bias,
                                                 unsigned short* __restrict__ zx) {
  __shared__ __align__(16) float XeT[96][68];
  __shared__ __align__(16) float WT[96][68];
  int mt = blockIdx.x;              // 0..1023
  int m0 = mt * 64;
  int tid = threadIdx.x;
  for (int idx = tid; idx < 6144; idx += 256) {
    int r = idx / 96, k = idx - r * 96;
    size_t m = (size_t)(m0 + r);
    float v = (k < 64) ? x[m * 64 + k] : emb[m * 32 + (k - 64)];
    XeT[k][r] = v;
  }
  int ty = tid >> 4, tx = tid & 15;
  int r0 = ty * 4, c0 = tx * 4;
  for (int nt = 0; nt < 16; nt++) {
    int n0 = nt * 64;
    __syncthreads();                // protect WT vs previous iter's readers (covers XeT stage on iter 0)
    for (int idx = tid; idx < 6144; idx += 256) {
      int c = idx / 96, k = idx - c * 96;
      WT[k][c] = Wih[(size_t)(n0 + c) * 96 + k];
    }
    __syncthreads();
    float acc[4][4] = {};
    for (int k = 0; k < 96; k++) {
      float4 a = *(const float4*)&XeT[k][r0];
      float4 wv4 = *(const float4*)&WT[k][c0];
      float av[4] = {a.x, a.y, a.z, a.w};
      float wv[4] = {wv4.x, wv4.y, wv4.z, wv4.w};
#pragma unroll
      for (int i = 0; i < 4; i++)
#pragma unroll
        for (int jj = 0; jj < 4; jj++) acc[i][jj] += av[i] * wv[jj];
    }
#pragma unroll
    for (int i = 0; i < 4; i++) {
      size_t m = (size_t)(m0 + r0 + i);
#pragma unroll
      for (int jj = 0; jj < 4; jj++) {
        int col = n0 + c0 + jj;
        zx[m * 1024 + (size_t)col] = f16bits(acc[i][jj] + bias[col]);
      }
    }
  }
}

// ---------------- k3: persistent per-batch LSTM (transposed i8 MFMA, distributed tail) ----------------
__global__ __launch_bounds__(1024, 4) void lstm_kernel(const unsigned short* __restrict__ zx,
                                                       const v4i* __restrict__ wpk,
                                                       float* __restrict__ out) {
  __shared__ __align__(16) char hq[2][256];
  const int t = threadIdx.x, b = blockIdx.x;
  const int w = t >> 6, lane = t & 63, q = lane >> 4, n = lane & 15;

  // full W_hh residency: 16 frags x 16B i8 = 64 regs (B-operand; AGPR-friendly)
  v4i wf[16];
#pragma unroll
  for (int i = 0; i < 16; i++) wf[i] = wpk[i * 1024 + t];

  if (t < 128) ((unsigned int*)hq)[t] = 0;   // zero both h buffers (2x256 i8)
  __syncthreads();

  // wave-priority stagger: same-SIMD waves at prio 3,2,1,0 (robust to either wave->SIMD map)
  {
    int pr = 3 - (((w >> 2) ^ w) & 3);
    if (pr == 3) __builtin_amdgcn_s_setprio(3);
    else if (pr == 2) __builtin_amdgcn_s_setprio(2);
    else if (pr == 1) __builtin_amdgcn_s_setprio(1);
  }

  const float dq = 1.0f / (2032.0f * 127.0f);
  const int u = w * 16 + n;                       // this lane's unit
  const bool isg = (q == 2);                      // lane's gate = q ; gate 2 is tanh
  const float sc = isg ? 2.88539008f : 1.44269504f;
  const unsigned short* zp = zx + (size_t)b * (2048u * 1024u) + (unsigned)(q * 256 + u);
  const bool wr = (q == 0);
  float* op = out + (size_t)b * (2048u * 256u) + u;
  char* hn0 = &hq[0][u];
  const int bpb = n << 2;                         // bpermute byte base: lanes (g*16+n), g=0..3
  const v4i zerov = {0, 0, 0, 0};                 // persistent MFMA C operand (D != C)

  float cst = 0.f, hlast = 0.f;
  unsigned short za = zp[0];
  unsigned short zb = zp[1024];

  for (int s = 0; s < 2048; s++) {
    const char* hc = hq[s & 1];
    int sp = s + 2; if (sp > 2047) sp = 2047;
    unsigned short zc = zp[(size_t)sp << 10];

    // A-frags: broadcast h chunk (16B per 16-lane group -> all M rows = h)
    v4i bq[4];
#pragma unroll
    for (int c = 0; c < 4; c++) bq[c] = *(const v4i*)(hc + c * 64 + q * 16);

    // acc[g] col n = z[g][w*16+n]; rows are h-replicas -> reg 0, identical across q
    v4i acc[4];
#pragma unroll
    for (int gg = 0; gg < 4; gg++)
      acc[gg] = __builtin_amdgcn_mfma_i32_16x16x64_i8(bq[0], wf[gg * 4 + 0], zerov, 0, 0, 0);
#pragma unroll
    for (int c = 1; c < 4; c++)
#pragma unroll
      for (int gg = 0; gg < 4; gg++)
        acc[gg] = __builtin_amdgcn_mfma_i32_16x16x64_i8(bq[c], wf[gg * 4 + c], acc[gg], 0, 0, 0);

    // lane (q,n) activates gate q of unit u: select acc[q][0] (3 scalar cndmask)
    int tlo = (q & 1) ? acc[1][0] : acc[0][0];
    int thi = (q & 1) ? acc[3][0] : acc[2][0];
    int zi  = (q & 2) ? thi : tlo;

    float z = (float)zi * dq + h2f(za);
    float e = __builtin_amdgcn_exp2f(-sc * z);
    float r = __builtin_amdgcn_rcpf(1.f + e);
    float a = isg ? (2.f * r - 1.f) : r;           // gate q: tanh if q==2 else sigmoid
    // gather i,f,g,o of unit u from lanes (g*16+n), g=0..3 (wave-wide bpermute pull)
    int ab = __builtin_bit_cast(int, a);
    float ai = __builtin_bit_cast(float, __builtin_amdgcn_ds_bpermute(bpb + 0, ab));
    float af = __builtin_bit_cast(float, __builtin_amdgcn_ds_bpermute(bpb + 64, ab));
    float ag = __builtin_bit_cast(float, __builtin_amdgcn_ds_bpermute(bpb + 128, ab));
    float ao = __builtin_bit_cast(float, __builtin_amdgcn_ds_bpermute(bpb + 192, ab));
    float cn = af * cst + ai * ag;
    float e2 = __builtin_amdgcn_exp2f(-2.88539008f * cn);
    float th = 2.f * __builtin_amdgcn_rcpf(1.f + e2) - 1.f;
    float h = ao * th;
    cst = cn;
    hlast = h;
    if (wr) {
      hn0[((s & 1) ^ 1) * 256] = (char)(int)rintf(h * 127.0f);   // i8 h feedback
      op[(size_t)s * 256] = h;                                    // fp32 output
    }
    za = zb; zb = zc;
    __syncthreads();
  }
  if (wr) {
    out[16777216u + (size_t)b * 256 + u] = hlast;          // final h
    out[16777216u + 8192u + (size_t)b * 256 + u] = cst;    // final c
  }
}

extern "C" void kernel_launch(void* const* d_in, const int* in_sizes, int n_in,
                              void* d_out, int out_size, void* d_ws, size_t ws_size,
                              hipStream_t stream) {
  const float* x = (const float*)d_in[0];
  const float* emb = (const float*)d_in[1];
  const float* W_ih = (const float*)d_in[2];
  const float* W_hh = (const float*)d_in[3];
  const float* bias = (const float*)d_in[4];
  float* out = (float*)d_out;
  char* ws = (char*)d_ws;

  unsigned short* zx = (unsigned short*)ws;
  uint4* wpk = (uint4*)(ws + WPK_OFF);

  size_t need = (size_t)WPK_OFF + 262144u;
  if (ws_size < need) {
    fprintf(stderr, "kernel_launch: ws too small: %zu < %zu\n", ws_size, need);
  }

  pack_kernel<<<dim3(16), dim3(1024), 0, stream>>>(W_hh, wpk);
  zx_kernel<<<dim3(1024), dim3(256), 0, stream>>>(x, emb, W_ih, bias, zx);
  lstm_kernel<<<dim3(32), dim3(1024), 0, stream>>>(zx, (const v4i*)wpk, out);
}

// Round 7
// 1699.297 us; speedup vs baseline: 1.1299x; 1.0098x over previous
//
#include <hip/hip_runtime.h>
#include <hip/hip_fp16.h>
#include <cstdio>

// EmbeddingCellLSTM: B=32, S=2048, IN=64, EMB=32, H=256, 4H=1024
//  k1 pack_kernel : W_hh fp32 -> i8 (scale 2032) 16B K-fragments (lane&15 -> W row, lane>>4 -> K-chunk).
//  k2 zx_kernel   : zx = (concat(x,emb) @ W_ih^T + b) fp16; block = 64-row stripe, stages x once.
//  k3 lstm_kernel : transposed MFMA (r5/r6 verified): acc[g] = mfma(A=h_bcast, B=W_frag, C=0);
//                   lane (q,n) takes gate q of unit u=w*16+n (3 cndmask select), ONE activation,
//                   4 wave-wide bpermute gather i,f,g,o, c/h update (x4 q-replicas), q==0 writes.
//                   r7 changes: (a) 2x UNROLL -> compile-time h-buffer alternation (no s&1
//                   selects), named zx regs reloaded at distance-2 (no mov chain), no sp clamp
//                   (prefetch for s>=2048 reads harmlessly into allocated wpk region);
//                   (b) prio: static stagger 3,2,1,0 during MFMA cluster, setprio(0) in tail so
//                   tail waves yield issue to waves still in MFMAs.
//  Measured floor: matrix pipe = 64 MFMA-inst/SIMD/step x 16 cyc = 1024 cyc/step (r4=r5=r6).
//  r6 step = 1730 cyc = 1024 + ~700 exposed tail; this round targets the tail's inst count.

#define WPK_OFF (134217728u)   // zx = 32*2048*1024*2 bytes, then wpk 256 KB

typedef int v4i __attribute__((ext_vector_type(4)));

static __device__ __forceinline__ unsigned short f16bits(float v) {
  _Float16 h = (_Float16)v;
  return __builtin_bit_cast(unsigned short, h);
}

static __device__ __forceinline__ float h2f(unsigned short b) {
  return (float)__builtin_bit_cast(_Float16, b);
}

// ---------------- k1: pack W_hh -> i8 MFMA K-fragments ----------------
// tile = g*4+c ; thread t -> w=t>>6, lane: m=lane&15 (row), q=lane>>4
// frag byte j = W[g*256 + 16w + m][c*64 + q*16 + j] ; wq = rint(w*2032), |w|<1/16 -> |wq|<=127
__global__ __launch_bounds__(1024) void pack_kernel(const float* __restrict__ Whh,
                                                    uint4* __restrict__ wpk) {
  int tile = blockIdx.x;            // 0..15
  int g = tile >> 2, c = tile & 3;
  int t = threadIdx.x;
  int w = t >> 6, lane = t & 63, m = lane & 15, q = lane >> 4;
  int row = g * 256 + w * 16 + m;
  const float* src = Whh + row * 256 + c * 64 + q * 16;
  unsigned int pk[4];
#pragma unroll
  for (int d = 0; d < 4; d++) {
    unsigned int v = 0;
#pragma unroll
    for (int e = 0; e < 4; e++) {
      int qv = (int)rintf(src[d * 4 + e] * 2032.0f);
      v |= ((unsigned int)(qv & 255)) << (8 * e);
    }
    pk[d] = v;
  }
  uint4 o; o.x = pk[0]; o.y = pk[1]; o.z = pk[2]; o.w = pk[3];
  wpk[tile * 1024 + t] = o;
}

// ---------------- k2: zx = concat(x,emb) @ W_ih^T + b (fp16, natural row order) ----------------
// One block per 64-row stripe; x/emb staged once, 16 column tiles looped in-block.
__global__ __launch_bounds__(256) void zx_kernel(const float* __restrict__ x,
                                                 const float* __restrict__ emb,
                                                 const float* __restrict__ Wih,
                                                 const float* __restrict__ bias,
                                                 unsigned short* __restrict__ zx) {
  __shared__ __align__(16) float XeT[96][68];
  __shared__ __align__(16) float WT[96][68];
  int mt = blockIdx.x;              // 0..1023
  int m0 = mt * 64;
  int tid = threadIdx.x;
  for (int idx = tid; idx < 6144; idx += 256) {
    int r = idx / 96, k = idx - r * 96;
    size_t m = (size_t)(m0 + r);
    float v = (k < 64) ? x[m * 64 + k] : emb[m * 32 + (k - 64)];
    XeT[k][r] = v;
  }
  int ty = tid >> 4, tx = tid & 15;
  int r0 = ty * 4, c0 = tx * 4;
  for (int nt = 0; nt < 16; nt++) {
    int n0 = nt * 64;
    __syncthreads();                // protect WT vs previous iter's readers (covers XeT stage on iter 0)
    for (int idx = tid; idx < 6144; idx += 256) {
      int c = idx / 96, k = idx - c * 96;
      WT[k][c] = Wih[(size_t)(n0 + c) * 96 + k];
    }
    __syncthreads();
    float acc[4][4] = {};
    for (int k = 0; k < 96; k++) {
      float4 a = *(const float4*)&XeT[k][r0];
      float4 wv4 = *(const float4*)&WT[k][c0];
      float av[4] = {a.x, a.y, a.z, a.w};
      float wv[4] = {wv4.x, wv4.y, wv4.z, wv4.w};
#pragma unroll
      for (int i = 0; i < 4; i++)
#pragma unroll
        for (int jj = 0; jj < 4; jj++) acc[i][jj] += av[i] * wv[jj];
    }
#pragma unroll
    for (int i = 0; i < 4; i++) {
      size_t m = (size_t)(m0 + r0 + i);
#pragma unroll
      for (int jj = 0; jj < 4; jj++) {
        int col = n0 + c0 + jj;
        zx[m * 1024 + (size_t)col] = f16bits(acc[i][jj] + bias[col]);
      }
    }
  }
}

// ---------------- k3: persistent per-batch LSTM (transposed i8 MFMA, 2x unrolled) ----------------
__global__ __launch_bounds__(1024, 4) void lstm_kernel(const unsigned short* __restrict__ zx,
                                                       const v4i* __restrict__ wpk,
                                                       float* __restrict__ out) {
  __shared__ __align__(16) char hq[2][256];
  const int t = threadIdx.x, b = blockIdx.x;
  const int w = t >> 6, lane = t & 63, q = lane >> 4, n = lane & 15;

  // full W_hh residency: 16 frags x 16B i8 = 64 regs (B-operand; AGPR-friendly)
  v4i wf[16];
#pragma unroll
  for (int i = 0; i < 16; i++) wf[i] = wpk[i * 1024 + t];

  if (t < 128) ((unsigned int*)hq)[t] = 0;   // zero both h buffers (2x256 i8)
  __syncthreads();

  // static stagger prio for the MFMA phase (robust to either wave->SIMD map)
  const int pr = 3 - (((w >> 2) ^ w) & 3);

  const float dq = 1.0f / (2032.0f * 127.0f);
  const int u = w * 16 + n;                       // this lane's unit
  const bool isg = (q == 2);                      // lane's gate = q ; gate 2 is tanh
  const float sc = isg ? 2.88539008f : 1.44269504f;
  const unsigned short* zp = zx + (size_t)b * (2048u * 1024u) + (unsigned)(q * 256 + u);
  const bool wr = (q == 0);
  float* op = out + (size_t)b * (2048u * 256u) + u;
  char* hw0 = &hq[1][u];                          // written in even steps (for s+1)
  char* hw1 = &hq[0][u];                          // written in odd steps
  const int bpb = n << 2;                         // bpermute byte base: lanes (g*16+n), g=0..3
  const v4i zerov = {0, 0, 0, 0};                 // persistent MFMA C operand (D != C)

  float cst = 0.f, hlast = 0.f;
  unsigned short za = zp[0];                      // zx for even step s
  unsigned short zb = zp[1024];                   // zx for odd step s+1

#define LSTM_STEP(HC, HWPTR, ZREG, SIDX)                                              \
  {                                                                                   \
    const char* hc = (HC);                                                            \
    v4i bq[4];                                                                        \
    _Pragma("unroll")                                                                 \
    for (int c = 0; c < 4; c++) bq[c] = *(const v4i*)(hc + c * 64 + q * 16);          \
    unsigned short zu = ZREG;                                                         \
    ZREG = zp[(size_t)((SIDX) + 2) << 10];  /* distance-2 prefetch; tail OOB-safe */  \
    if (pr == 3) __builtin_amdgcn_s_setprio(3);                                       \
    else if (pr == 2) __builtin_amdgcn_s_setprio(2);                                  \
    else if (pr == 1) __builtin_amdgcn_s_setprio(1);                                  \
    v4i acc[4];                                                                       \
    _Pragma("unroll")                                                                 \
    for (int gg = 0; gg < 4; gg++)                                                    \
      acc[gg] = __builtin_amdgcn_mfma_i32_16x16x64_i8(bq[0], wf[gg * 4 + 0], zerov, 0, 0, 0); \
    _Pragma("unroll")                                                                 \
    for (int c = 1; c < 4; c++)                                                       \
      _Pragma("unroll")                                                               \
      for (int gg = 0; gg < 4; gg++)                                                  \
        acc[gg] = __builtin_amdgcn_mfma_i32_16x16x64_i8(bq[c], wf[gg * 4 + c], acc[gg], 0, 0, 0); \
    __builtin_amdgcn_s_setprio(0);                                                    \
    int tlo = (q & 1) ? acc[1][0] : acc[0][0];                                        \
    int thi = (q & 1) ? acc[3][0] : acc[2][0];                                        \
    int zi  = (q & 2) ? thi : tlo;                                                    \
    float z = (float)zi * dq + h2f(zu);                                               \
    float e = __builtin_amdgcn_exp2f(-sc * z);                                        \
    float r = __builtin_amdgcn_rcpf(1.f + e);                                         \
    float a = isg ? (2.f * r - 1.f) : r;                                              \
    int ab = __builtin_bit_cast(int, a);                                              \
    float ai = __builtin_bit_cast(float, __builtin_amdgcn_ds_bpermute(bpb + 0, ab));  \
    float af = __builtin_bit_cast(float, __builtin_amdgcn_ds_bpermute(bpb + 64, ab)); \
    float ag = __builtin_bit_cast(float, __builtin_amdgcn_ds_bpermute(bpb + 128, ab));\
    float ao = __builtin_bit_cast(float, __builtin_amdgcn_ds_bpermute(bpb + 192, ab));\
    float cn = af * cst + ai * ag;                                                    \
    float e2 = __builtin_amdgcn_exp2f(-2.88539008f * cn);                             \
    float th = 2.f * __builtin_amdgcn_rcpf(1.f + e2) - 1.f;                           \
    float h = ao * th;                                                                \
    cst = cn;                                                                         \
    hlast = h;                                                                        \
    if (wr) {                                                                         \
      *(HWPTR) = (char)(int)rintf(h * 127.0f);                                        \
      op[(size_t)(SIDX) * 256] = h;                                                   \
    }                                                                                 \
    __syncthreads();                                                                  \
  }

  for (int s = 0; s < 2048; s += 2) {
    LSTM_STEP(hq[0], hw0, za, s)       // even: read buf0, write buf1
    LSTM_STEP(hq[1], hw1, zb, s + 1)   // odd : read buf1, write buf0
  }
#undef LSTM_STEP

  if (wr) {
    out[16777216u + (size_t)b * 256 + u] = hlast;          // final h
    out[16777216u + 8192u + (size_t)b * 256 + u] = cst;    // final c
  }
}

extern "C" void kernel_launch(void* const* d_in, const int* in_sizes, int n_in,
                              void* d_out, int out_size, void* d_ws, size_t ws_size,
                              hipStream_t stream) {
  const float* x = (const float*)d_in[0];
  const float* emb = (const float*)d_in[1];
  const float* W_ih = (const float*)d_in[2];
  const float* W_hh = (const float*)d_in[3];
  const float* bias = (const float*)d_in[4];
  float* out = (float*)d_out;
  char* ws = (char*)d_ws;

  unsigned short* zx = (unsigned short*)ws;
  uint4* wpk = (uint4*)(ws + WPK_OFF);

  size_t need = (size_t)WPK_OFF + 262144u;
  if (ws_size < need) {
    fprintf(stderr, "kernel_launch: ws too small: %zu < %zu\n", ws_size, need);
  }

  pack_kernel<<<dim3(16), dim3(1024), 0, stream>>>(W_hh, wpk);
  zx_kernel<<<dim3(1024), dim3(256), 0, stream>>>(x, emb, W_ih, bias, zx);
  lstm_kernel<<<dim3(32), dim3(1024), 0, stream>>>(zx, (const v4i*)wpk, out);
}